// Round 15
// baseline (101.312 us; speedup 1.0000x reference)
//
#include <hip/hip_runtime.h>

// MFVIConstituency: q[b,i,j] = s_con[b,i,j] + sum_k sig(q)[b,j,k] * s_bin[b,i,j,k] * (i!=k)*(j!=k)*mask[b,i,j]
// MAX_ITER=3, output sigmoid(q). Memory-bound; byte floor 566 MB
// (227 fp32 s_bin read + 113 fp16 masked-copy write + 2x113 read).
//
// R15 = R14 minus the sig0 pre-kernel: K1 applies sigmoid to s_con rows inline
// (R6-proven; transcendentals hide under the 340 MB stream). 3 dispatches.
//  - K1: fp32 s_bin NT read, k-mask folded, fp16 copy via paired 16B stores,
//        iter1 fused, sighA out fp16
//  - K2/K3: 8 lanes/row, all-16B halfx8 loads of copy + fp16 sig
// NT only on the one-shot fp32 s_bin read (R13 proved NT on the copy hurts).
// Persistent/grid-barrier variants (R9-R12) all lose: cross-XCD barriers
// ~10us vs ~2-3us dispatch boundaries; L3 residency gives no rate benefit.

#define S_DIM 192
#define SS (S_DIM * S_DIM)
#define B_DIM 8
#define NROWS (B_DIM * SS)   // 294912 outputs

typedef float    floatx4 __attribute__((ext_vector_type(4)));
typedef _Float16 halfx4  __attribute__((ext_vector_type(4)));
typedef _Float16 halfx8  __attribute__((ext_vector_type(8)));

__device__ __forceinline__ float sigmoidf(float x) {
    return 1.0f / (1.0f + __expf(-x));
}

// K1: fp32 s_bin (NT) -> masked fp16 copy (16B paired stores) + fused iter1 -> sighA (fp16)
__global__ __launch_bounds__(256) void fvi_first_kernel(const float* __restrict__ s_con,
                                                        const float* __restrict__ s_bin,
                                                        const int* __restrict__ mask,
                                                        halfx8* __restrict__ sbh8,
                                                        _Float16* __restrict__ sigh_out) {
    const int wave = threadIdx.x >> 6;
    const int lane = threadIdx.x & 63;
    const int grp  = lane >> 4;                      // 4 rows per wave
    const int sub  = lane & 15;                      // 16 lanes per row
    const int row  = (blockIdx.x * 4 + wave) * 4 + grp;

    const int b   = row / SS;
    const int rem = row - b * SS;
    const int i   = rem / S_DIM;
    const int j   = rem - i * S_DIM;

    const floatx4* __restrict__ srow = reinterpret_cast<const floatx4*>(s_bin + (size_t)row * S_DIM);
    const float4*  __restrict__ grow = reinterpret_cast<const float4*>(s_con + (size_t)(b * SS + j * S_DIM));
    halfx8* __restrict__ hrow = sbh8 + (size_t)row * (S_DIM / 8);

    float dot = 0.0f;
    #pragma unroll
    for (int c = 0; c < 3; ++c) {
        const int f4 = sub + (c << 4);               // 0..47
        floatx4 sv = __builtin_nontemporal_load(srow + f4);
        float4  gv = grow[f4];                       // s_con[b,j,k0..k0+3] (1.2 MB, L2-hot)
        const int k0 = f4 << 2;
        const float m0 = (k0 + 0 != i && k0 + 0 != j) ? sv.x : 0.0f;
        const float m1 = (k0 + 1 != i && k0 + 1 != j) ? sv.y : 0.0f;
        const float m2 = (k0 + 2 != i && k0 + 2 != j) ? sv.z : 0.0f;
        const float m3 = (k0 + 3 != i && k0 + 3 != j) ? sv.w : 0.0f;
        dot += m0 * sigmoidf(gv.x) + m1 * sigmoidf(gv.y)
             + m2 * sigmoidf(gv.z) + m3 * sigmoidf(gv.w);
        halfx4 hv;
        hv.x = (_Float16)m0; hv.y = (_Float16)m1;
        hv.z = (_Float16)m2; hv.w = (_Float16)m3;
        // pair lanes: even lane stores 16B (own 8B + partner's 8B)
        int2 hb = __builtin_bit_cast(int2, hv);
        int px = __shfl_down(hb.x, 1, 64);
        int py = __shfl_down(hb.y, 1, 64);
        if (!(sub & 1)) {
            int4 w4 = { hb.x, hb.y, px, py };
            hrow[f4 >> 1] = __builtin_bit_cast(halfx8, w4);
        }
    }

    dot += __shfl_xor(dot, 1, 64);
    dot += __shfl_xor(dot, 2, 64);
    dot += __shfl_xor(dot, 4, 64);
    dot += __shfl_xor(dot, 8, 64);

    if (sub == 0) {
        float q = s_con[row] + (mask[row] ? dot : 0.0f);
        sigh_out[row] = (_Float16)sigmoidf(q);
    }
}

// K2/K3: 8 lanes/row, 3x halfx8 copy + 3x halfx8 sig (all 16B loads)
template <bool LAST>
__global__ __launch_bounds__(256) void fvi_iter_kernel(const float* __restrict__ s_con,
                                                       const halfx8* __restrict__ sbh8,
                                                       const int* __restrict__ mask,
                                                       const _Float16* __restrict__ sigh_in,
                                                       _Float16* __restrict__ sigh_out,
                                                       float* __restrict__ out32) {
    const int wave = threadIdx.x >> 6;
    const int lane = threadIdx.x & 63;
    const int grp  = lane >> 3;                      // 8 rows per wave
    const int sub  = lane & 7;                       // 8 lanes per row
    const int row  = (blockIdx.x * 4 + wave) * 8 + grp;

    const int b   = row / SS;
    const int rem = row - b * SS;
    const int j   = rem - (rem / S_DIM) * S_DIM;

    const halfx8* __restrict__ hrow = sbh8 + (size_t)row * (S_DIM / 8);
    const halfx8* __restrict__ grow = reinterpret_cast<const halfx8*>(sigh_in + (size_t)(b * SS + j * S_DIM));

    float dot = 0.0f;
    #pragma unroll
    for (int c = 0; c < 3; ++c) {
        const int f8 = sub + (c << 3);               // 0..23
        halfx8 h = hrow[f8];
        halfx8 g = grow[f8];
        dot += (float)h[0] * (float)g[0] + (float)h[1] * (float)g[1]
             + (float)h[2] * (float)g[2] + (float)h[3] * (float)g[3]
             + (float)h[4] * (float)g[4] + (float)h[5] * (float)g[5]
             + (float)h[6] * (float)g[6] + (float)h[7] * (float)g[7];
    }

    dot += __shfl_xor(dot, 1, 64);
    dot += __shfl_xor(dot, 2, 64);
    dot += __shfl_xor(dot, 4, 64);

    if (sub == 0) {
        float q = s_con[row] + (mask[row] ? dot : 0.0f);
        float s = sigmoidf(q);
        if (LAST) out32[row] = s; else sigh_out[row] = (_Float16)s;
    }
}

extern "C" void kernel_launch(void* const* d_in, const int* in_sizes, int n_in,
                              void* d_out, int out_size, void* d_ws, size_t ws_size,
                              hipStream_t stream) {
    const float* s_con = (const float*)d_in[0];
    const float* s_bin = (const float*)d_in[1];
    const int*   mask  = (const int*)d_in[2];   // harness widens bool -> int32
    float* out = (float*)d_out;

    _Float16* sighA = (_Float16*)d_ws;
    _Float16* sighB = sighA + NROWS;
    halfx8*   sbh8  = reinterpret_cast<halfx8*>(sighB + NROWS);  // 113 MB fp16 masked copy

    fvi_first_kernel<<<NROWS / 16, 256, 0, stream>>>(s_con, s_bin, mask, sbh8, sighA);
    fvi_iter_kernel<false><<<NROWS / 32, 256, 0, stream>>>(s_con, sbh8, mask, sighA, sighB, nullptr);
    fvi_iter_kernel<true ><<<NROWS / 32, 256, 0, stream>>>(s_con, sbh8, mask, sighB, nullptr, out);
}